// Round 2
// baseline (608.884 us; speedup 1.0000x reference)
//
#include <hip/hip_runtime.h>

typedef unsigned short u16;
typedef __attribute__((ext_vector_type(8))) short bf16x8;
typedef __attribute__((ext_vector_type(8))) unsigned short u16x8;
typedef __attribute__((ext_vector_type(4))) float f32x4;

#define L_SEQ 2048
#define NTOK 4096   // B*L
#define DMODEL 1024
#define DEXP 2048
#define NH 16
#define DH 128

__device__ __forceinline__ u16 f2bf(float f) {
    unsigned u = __float_as_uint(f);
    unsigned r = (u + 0x7FFFu + ((u >> 16) & 1u)) >> 16;
    return (u16)r;
}
__device__ __forceinline__ float bf2f(u16 h) {
    return __uint_as_float(((unsigned)h) << 16);
}

// ---------------- convert + transpose fp32 -> bf16, out[c*R + r] = in[r*C + c]
__global__ void conv_transpose(const float* __restrict__ in, u16* __restrict__ out, int R, int C) {
    __shared__ unsigned tile[32][33];
    int c0 = blockIdx.x * 32, r0 = blockIdx.y * 32;
    int tx = threadIdx.x, ty = threadIdx.y;
    for (int j = 0; j < 32; j += 8)
        tile[ty + j][tx] = (unsigned)f2bf(in[(size_t)(r0 + ty + j) * C + c0 + tx]);
    __syncthreads();
    for (int j = 0; j < 32; j += 8)
        out[(size_t)(c0 + ty + j) * R + r0 + tx] = (u16)tile[tx][ty + j];
}

// ---------------- layernorm over 1024, out bf16 or fp32
__global__ __launch_bounds__(256) void ln_fwd(const float* __restrict__ x, const float* __restrict__ g,
                                              const float* __restrict__ bta, void* __restrict__ outp,
                                              int out_bf16) {
    int row = blockIdx.x;
    int t = threadIdx.x;
    const float* xr = x + (size_t)row * DMODEL;
    float4 xv = *(const float4*)&xr[t * 4];
    float s = xv.x + xv.y + xv.z + xv.w;
    float s2 = xv.x * xv.x + xv.y * xv.y + xv.z * xv.z + xv.w * xv.w;
    for (int off = 32; off >= 1; off >>= 1) {
        s += __shfl_xor(s, off);
        s2 += __shfl_xor(s2, off);
    }
    __shared__ float red[10];
    int w = t >> 6;
    if ((t & 63) == 0) { red[w] = s; red[4 + w] = s2; }
    __syncthreads();
    if (t == 0) {
        red[8] = red[0] + red[1] + red[2] + red[3];
        red[9] = red[4] + red[5] + red[6] + red[7];
    }
    __syncthreads();
    float mu = red[8] * (1.0f / DMODEL);
    float var = red[9] * (1.0f / DMODEL) - mu * mu;
    float rstd = rsqrtf(var + 1e-5f);
    float vals[4] = {xv.x, xv.y, xv.z, xv.w};
    for (int e = 0; e < 4; e++) {
        int c = t * 4 + e;
        float y = (vals[e] - mu) * rstd * g[c] + bta[c];
        if (out_bf16) ((u16*)outp)[(size_t)row * DMODEL + c] = f2bf(y);
        else          ((float*)outp)[(size_t)row * DMODEL + c] = y;
    }
}

// ---------------- GEMM: C[M,N] = A[M,K](bf16) * B[K,N], B given as BT[N,K] bf16
__device__ __forceinline__ void store_out(u16* C, size_t idx, float v) { C[idx] = f2bf(v); }
__device__ __forceinline__ void store_out(float* C, size_t idx, float v) { C[idx] = v; }

#define APITCH 40  // 32 + 8 pad: full bank spread per 16-lane b128 phase

template <typename OutT>
__global__ __launch_bounds__(256) void gemm_bt(const u16* __restrict__ A, const u16* __restrict__ BT,
                                               OutT* __restrict__ C, int M, int N, int K) {
    __shared__ u16 a_s[128 * APITCH];
    __shared__ u16 b_s[128 * APITCH];
    int tid = threadIdx.x;
    int m0 = blockIdx.y * 128, n0 = blockIdx.x * 128;
    int w = tid >> 6, lane = tid & 63, quad = lane >> 4, ln = lane & 15;
    int wr = (w >> 1) * 64, wc = (w & 1) * 64;
    f32x4 zero4 = {0.f, 0.f, 0.f, 0.f};
    f32x4 acc[4][4];
    for (int r = 0; r < 4; r++)
        for (int c = 0; c < 4; c++) acc[r][c] = zero4;

    int srow = tid >> 1;
    int sseg = (tid & 1) * 16;
    const u16* Ap = A + (size_t)(m0 + srow) * K + sseg;
    const u16* Bp = BT + (size_t)(n0 + srow) * K + sseg;
    u16* asw = &a_s[srow * APITCH + sseg];
    u16* bsw = &b_s[srow * APITCH + sseg];

    for (int k0 = 0; k0 < K; k0 += 32) {
        __syncthreads();
        *(int4*)asw       = *(const int4*)(Ap + k0);
        *(int4*)(asw + 8) = *(const int4*)(Ap + k0 + 8);
        *(int4*)bsw       = *(const int4*)(Bp + k0);
        *(int4*)(bsw + 8) = *(const int4*)(Bp + k0 + 8);
        __syncthreads();
        bf16x8 af[4], bfr[4];
        for (int r = 0; r < 4; r++) af[r]  = *(const bf16x8*)&a_s[(wr + r * 16 + ln) * APITCH + quad * 8];
        for (int c = 0; c < 4; c++) bfr[c] = *(const bf16x8*)&b_s[(wc + c * 16 + ln) * APITCH + quad * 8];
        for (int r = 0; r < 4; r++)
            for (int c = 0; c < 4; c++)
                acc[r][c] = __builtin_amdgcn_mfma_f32_16x16x32_bf16(af[r], bfr[c], acc[r][c], 0, 0, 0);
    }
    for (int r = 0; r < 4; r++)
        for (int c = 0; c < 4; c++)
            for (int e = 0; e < 4; e++) {
                int row = m0 + wr + r * 16 + quad * 4 + e;
                int col = n0 + wc + c * 16 + ln;
                store_out(C, (size_t)row * N + col, acc[r][c][e]);
            }
}

// ---------------- smear: k_sm[tok,c] = (1-s)*k[tok,c] + s*k[tok-1,c]
__global__ __launch_bounds__(256) void smear_kernel(const u16* __restrict__ qkvp,
                                                    const float* __restrict__ smear_f,
                                                    u16* __restrict__ k_sm) {
    int gid = blockIdx.x * 256 + threadIdx.x;
    int base = gid * 8;
    int bl = base >> 11;       // token index
    int c = base & 2047;
    int h = c >> 7;
    int l = bl & (L_SEQ - 1);
    float s = 1.0f / (1.0f + __expf(-smear_f[h]));
    u16x8 cur = *(const u16x8*)&qkvp[(size_t)bl * 8192 + 2048 + c];
    u16x8 prv = {0, 0, 0, 0, 0, 0, 0, 0};
    if (l > 0) prv = *(const u16x8*)&qkvp[(size_t)(bl - 1) * 8192 + 2048 + c];
    u16x8 outv;
    for (int u = 0; u < 8; u++) {
        float kc = bf2f(cur[u]);
        float kp = bf2f(prv[u]);
        outv[u] = f2bf((1.0f - s) * kc + s * kp);
    }
    *(u16x8*)&k_sm[(size_t)bl * 2048 + c] = outv;
}

// ---------------- per-(b,h) transpose of V: v_t[bh,d,l] = qkvp[tok, 4096 + h*128 + d]
__global__ void vT_kernel(const u16* __restrict__ qkvp, u16* __restrict__ v_t) {
    __shared__ unsigned tile[32][33];
    int l0 = blockIdx.x * 32, d0 = blockIdx.y * 32;
    int bh = blockIdx.z;
    int bb = bh >> 4, h = bh & 15;
    int tx = threadIdx.x, ty = threadIdx.y;
    size_t tokb = (size_t)bb * L_SEQ;
    for (int j = 0; j < 32; j += 8)
        tile[ty + j][tx] = (unsigned)qkvp[(tokb + l0 + ty + j) * 8192 + 4096 + h * DH + d0 + tx];
    __syncthreads();
    for (int j = 0; j < 32; j += 8)
        v_t[((size_t)bh * DH + d0 + ty + j) * L_SEQ + l0 + tx] = (u16)tile[tx][ty + j];
}

// ---------------- flash attention + SiLU(p) gating
#define QPITCH 136  // 128 + 8
#define VPITCH 40
#define PPITCH 40

__global__ __launch_bounds__(256) void attn_kernel(const u16* __restrict__ qkvp,
                                                   const u16* __restrict__ k_sm,
                                                   const u16* __restrict__ v_t,
                                                   u16* __restrict__ ag2,
                                                   const float* __restrict__ log_scale) {
    __shared__ u16 q_s[64 * QPITCH];
    __shared__ u16 k_s[32 * QPITCH];
    __shared__ u16 vt_s[128 * VPITCH];
    __shared__ u16 p_s[4 * 16 * PPITCH];
    int tid = threadIdx.x;
    int i0 = blockIdx.x * 64;
    int bh = blockIdx.y;
    int bb = bh >> 4, h = bh & 15;
    int w = tid >> 6, lane = tid & 63, quad = lane >> 4, ln = lane & 15;
    size_t tokb = (size_t)bb * L_SEQ;

    // load Q strip (64 x 128)
    for (int idx = tid; idx < 1024; idx += 256) {
        int row = idx >> 4, seg = idx & 15;
        *(int4*)&q_s[row * QPITCH + seg * 8] =
            *(const int4*)&qkvp[(tokb + i0 + row) * 8192 + h * DH + seg * 8];
    }

    float inv = 1.0f / (__expf(2.0f * log_scale[h]) * sqrtf((float)DH));
    float slope = (h < 8) ? exp2f(-8.0f * (float)h / 7.0f) : 0.0f;
    int si = i0 + w * 16;

    float m_i[4] = {-1e30f, -1e30f, -1e30f, -1e30f};
    float l_i[4] = {0.f, 0.f, 0.f, 0.f};
    f32x4 zero4 = {0.f, 0.f, 0.f, 0.f};
    f32x4 o_acc[8];
    for (int dt = 0; dt < 8; dt++) o_acc[dt] = zero4;

    int vseg = (tid & 1) * 16;
    int vd = tid >> 1;

    for (int j0 = 0; j0 <= i0 + 63; j0 += 32) {
        __syncthreads();
        // stage K (32 x 128)
        for (int idx = tid; idx < 512; idx += 256) {
            int row = idx >> 4, seg = idx & 15;
            *(int4*)&k_s[row * QPITCH + seg * 8] =
                *(const int4*)&k_sm[(tokb + j0 + row) * 2048 + h * DH + seg * 8];
        }
        // stage V^T (128 d x 32 j) — each thread covers 16 j-values (2 x int4)
        *(int4*)&vt_s[vd * VPITCH + vseg] =
            *(const int4*)&v_t[((size_t)bh * DH + vd) * L_SEQ + j0 + vseg];
        *(int4*)&vt_s[vd * VPITCH + vseg + 8] =
            *(const int4*)&v_t[((size_t)bh * DH + vd) * L_SEQ + j0 + vseg + 8];
        __syncthreads();
        if (j0 > si + 15) continue;

        // S = Q K^T for this wave's 16-row strip, two 16-col tiles
        f32x4 sc[2];
        for (int c = 0; c < 2; c++) {
            f32x4 acc = zero4;
            for (int kt = 0; kt < 4; kt++) {
                bf16x8 af  = *(const bf16x8*)&q_s[(w * 16 + ln) * QPITCH + kt * 32 + quad * 8];
                bf16x8 bfr = *(const bf16x8*)&k_s[(c * 16 + ln) * QPITCH + kt * 32 + quad * 8];
                acc = __builtin_amdgcn_mfma_f32_16x16x32_bf16(af, bfr, acc, 0, 0, 0);
            }
            sc[c] = acc;
        }
        float sv[2][4];
        for (int c = 0; c < 2; c++) {
            int j = j0 + c * 16 + ln;
            float aj = slope * (float)j;
            for (int r = 0; r < 4; r++) {
                int i = si + quad * 4 + r;
                float v = sc[c][r] * inv + aj;
                if (j > i) v += -1e10f;
                sv[c][r] = v;
            }
        }
        float mnew[4], alpha[4];
        for (int r = 0; r < 4; r++) {
            float mr = fmaxf(sv[0][r], sv[1][r]);
            for (int off = 1; off < 16; off <<= 1) mr = fmaxf(mr, __shfl_xor(mr, off));
            mnew[r] = fmaxf(m_i[r], mr);
            alpha[r] = __expf(m_i[r] - mnew[r]);
        }
        float p0[4], p1[4], ps_[4];
        u16* pw = &p_s[w * 16 * PPITCH];
        for (int r = 0; r < 4; r++) {
            p0[r] = __expf(sv[0][r] - mnew[r]);
            p1[r] = __expf(sv[1][r] - mnew[r]);
            u16 b0 = f2bf(p0[r]), b1 = f2bf(p1[r]);
            pw[(quad * 4 + r) * PPITCH + ln] = b0;
            pw[(quad * 4 + r) * PPITCH + 16 + ln] = b1;
            ps_[r] = bf2f(b0) + bf2f(b1);
        }
        for (int r = 0; r < 4; r++) {
            float s = ps_[r];
            for (int off = 1; off < 16; off <<= 1) s += __shfl_xor(s, off);
            l_i[r] = alpha[r] * l_i[r] + s;
            m_i[r] = mnew[r];
        }
        for (int dt = 0; dt < 8; dt++) {
            f32x4 o = o_acc[dt];
            for (int r = 0; r < 4; r++) o[r] *= alpha[r];
            o_acc[dt] = o;
        }
        asm volatile("s_waitcnt lgkmcnt(0)" ::: "memory");
        bf16x8 pa = *(const bf16x8*)&pw[ln * PPITCH + quad * 8];
        for (int dt = 0; dt < 8; dt++) {
            bf16x8 vf = *(const bf16x8*)&vt_s[(dt * 16 + ln) * VPITCH + quad * 8];
            o_acc[dt] = __builtin_amdgcn_mfma_f32_16x16x32_bf16(pa, vf, o_acc[dt], 0, 0, 0);
        }
    }

    // epilogue: normalize, SiLU(p) gate, store bf16
    for (int dt = 0; dt < 8; dt++) {
        for (int r = 0; r < 4; r++) {
            int i = si + quad * 4 + r;
            int dcol = dt * 16 + ln;
            float o = o_acc[dt][r] / l_i[r];
            float pv = bf2f(qkvp[(tokb + i) * 8192 + 6144 + h * DH + dcol]);
            float gate = pv / (1.0f + __expf(-pv));
            ag2[(tokb + i) * 2048 + h * DH + dcol] = f2bf(gate * o);
        }
    }
}

extern "C" void kernel_launch(void* const* d_in, const int* in_sizes, int n_in,
                              void* d_out, int out_size, void* d_ws, size_t ws_size,
                              hipStream_t stream) {
    const float* x       = (const float*)d_in[0];
    const float* ln1_g   = (const float*)d_in[1];
    const float* ln1_b   = (const float*)d_in[2];
    const float* ln2_g   = (const float*)d_in[3];
    const float* ln2_b   = (const float*)d_in[4];
    const float* w_in    = (const float*)d_in[5];
    const float* w_out   = (const float*)d_in[6];
    const float* smear_f = (const float*)d_in[7];
    const float* logsc   = (const float*)d_in[8];
    float* out = (float*)d_out;
    char* ws = (char*)d_ws;

    // ws layout (bytes)
    u16* w_inT   = (u16*)(ws + 0);                       // 16 MB  [8192,1024]
    u16* w_outT  = (u16*)(ws + (size_t)16777216);        //  4 MB  [1024,2048]
    u16* lnA     = (u16*)(ws + (size_t)20971520);        //  8 MB  [4096,1024]
    u16* qkvp    = (u16*)(ws + (size_t)29360128);        // 64 MB  [4096,8192]
    u16* k_sm    = (u16*)(ws + (size_t)96468992);        // 16 MB  [4096,2048]
    u16* ag2     = (u16*)(ws + (size_t)113246208);       // 16 MB  [4096,2048]
    float* out_pre = (float*)(ws + (size_t)96468992);    // alias k_sm (dead after attn)
    u16* v_t     = (u16*)(ws + 0);                       // alias w_inT (dead after gemm1)

    dim3 b32x8(32, 8);
    conv_transpose<<<dim3(8192 / 32, 1024 / 32), b32x8, 0, stream>>>(w_in, w_inT, 1024, 8192);
    conv_transpose<<<dim3(1024 / 32, 2048 / 32), b32x8, 0, stream>>>(w_out, w_outT, 2048, 1024);
    ln_fwd<<<NTOK, 256, 0, stream>>>(x, ln1_g, ln1_b, (void*)lnA, 1);
    gemm_bt<u16><<<dim3(8192 / 128, 4096 / 128), 256, 0, stream>>>(lnA, w_inT, qkvp, NTOK, 8192, 1024);
    smear_kernel<<<4096, 256, 0, stream>>>(qkvp, smear_f, k_sm);
    vT_kernel<<<dim3(L_SEQ / 32, DH / 32, 32), b32x8, 0, stream>>>(qkvp, v_t);
    attn_kernel<<<dim3(L_SEQ / 64, 32), 256, 0, stream>>>(qkvp, k_sm, v_t, ag2, logsc);
    gemm_bt<float><<<dim3(1024 / 128, 4096 / 128), 256, 0, stream>>>(ag2, w_outT, out_pre, NTOK, 1024, 2048);
    ln_fwd<<<NTOK, 256, 0, stream>>>(out_pre, ln2_g, ln2_b, (void*)out, 0);
}